// Round 15
// baseline (394.494 us; speedup 1.0000x reference)
//
#include <hip/hip_runtime.h>
#include <hip/hip_bf16.h>

typedef unsigned short u16;
typedef unsigned int u32;
typedef unsigned long long u64;
typedef __attribute__((ext_vector_type(8))) short short8;
typedef __attribute__((ext_vector_type(4))) float f32x4;

#define Bq 8
#define Cc 128
#define C4 512
#define Hh 256
#define Wf 256
#define H2 128
#define W2 128
#define HW2 16384
#define NPIX 131072.0f

__device__ __forceinline__ float gelu_f(float x) {
    float u = 1.5957691216057308f * (x + 0.044715f * x * x * x);
    float t = 1.0f - 2.0f / (__expf(u) + 1.0f);
    return 0.5f * x * (1.0f + t);
}
__device__ __forceinline__ float bf2f(u16 u) {
    union { float f; u32 i; } v; v.i = ((u32)u) << 16; return v.f;
}
__device__ __forceinline__ u16 f2bf(float f) {
    union { float f; u32 i; } v; v.f = f;
    u32 r = v.i + 0x7FFFu + ((v.i >> 16) & 1u);
    return (u16)(r >> 16);
}

// ---- weights f32 -> bf16; block 640: zero stats + LN-fold vectors ----
__global__ __launch_bounds__(256) void k_wconv(const float* __restrict__ w_c1,
                                               const float* __restrict__ pw1,
                                               const float* __restrict__ pw2,
                                               const float* __restrict__ w_c2,
                                               const float* __restrict__ gn_g,
                                               const float* __restrict__ gn_b,
                                               u16* __restrict__ wb,
                                               float* __restrict__ wbv,
                                               float* __restrict__ wgs,
                                               float* __restrict__ stats0) {
    if (blockIdx.x == 640) {
        for (int e = threadIdx.x; e < 22528; e += 256) stats0[e] = 0.f;
        int o = threadIdx.x;
        if (o < 128) {
            float a = 0.f, bv = 0.f;
            for (int c = 0; c < 128; ++c) {
                float w_ = pw1[o * 128 + c];
                a += w_ * gn_g[c];
                bv += w_ * gn_b[c];
            }
            wgs[o] = a;
            wbv[o] = bv;
        }
        return;
    }
    int i = blockIdx.x * 256 + threadIdx.x;   // 0..163839
    float v;
    if (i < 65536) {
        int o = i >> 9, kn = i & 511;
        int c = kn >> 2, dy = (kn >> 1) & 1, dx = kn & 1;
        float sdy = dy ? -1.f : 1.f, sdx = dx ? -1.f : 1.f;
        const float* wr = w_c1 + o * 512 + c;
        v = 0.5f * (wr[0] + sdy * wr[128] + sdx * wr[256] + sdy * sdx * wr[384]);
    } else if (i < 81920) v = pw1[i - 65536] * gn_g[(i - 65536) & 127];
    else if (i < 98304) v = pw2[i - 81920];
    else v = w_c2[i - 98304];
    wb[i] = f2bf(v);
}

// ---- fused DWT+conv1+BN1-stats: reads x f32 NCHW directly (512 thr) ----
__global__ __launch_bounds__(512) void k_conv1(const float* __restrict__ x,
                                               const u16* __restrict__ Wt,
                                               u16* __restrict__ Cout,
                                               float* __restrict__ statS,
                                               float* __restrict__ statQ) {
    __shared__ __align__(16) u16 lds[16384];
    __shared__ float sblk[128], qblk[128];
    const int t = threadIdx.x;
    const int lane = t & 63, w = t >> 6, wr = w & 1, wc = w >> 1;
    const int b = blockIdx.z, i = blockIdx.y;
    if (t < 128) { sblk[t] = 0.f; qblk[t] = 0.f; }

    const int r15 = lane & 15, kq = lane >> 4;
    const int half = t >> 8;
    const int colblk = t & 7, cc = (t >> 3) & 15, dy = (t >> 7) & 1;
    const int kbase = cc * 4 + dy * 2;
    const int gG = kbase >> 3, e2 = (kbase & 7) * 2;

    float4 xv[4];
    uint4 rb[2];
    {
        const float* xp = x + (((long)(b * Cc + cc)) * Hh + (2 * i + dy)) * Wf;
#pragma unroll
        for (int q = 0; q < 4; ++q) {
            int col = (half * 4 + q) * 32 + colblk * 4;
            xv[q] = *(const float4*)(xp + col);
        }
#pragma unroll
        for (int ii = 0; ii < 2; ++ii) {
            int s = ii * 512 + t;
            rb[ii] = *(const uint4*)(Wt + (long)(s >> 3) * 512 + (s & 7) * 8);
        }
    }

    f32x4 acc[4][2];
#pragma unroll
    for (int a2 = 0; a2 < 4; ++a2)
#pragma unroll
        for (int j2 = 0; j2 < 2; ++j2) acc[a2][j2] = (f32x4){0.f, 0.f, 0.f, 0.f};

    for (int k0 = 0; k0 < 512; k0 += 64) {
        __syncthreads();
#pragma unroll
        for (int q = 0; q < 4; ++q) {
            int col = (half * 4 + q) * 32 + colblk * 4;
            int j0 = col >> 1;
            u32 p0 = (u32)f2bf(xv[q].x) | ((u32)f2bf(xv[q].y) << 16);
            u32 p1 = (u32)f2bf(xv[q].z) | ((u32)f2bf(xv[q].w) << 16);
            *(u32*)((char*)lds + j0 * 128 + 16 * (gG ^ (j0 & 7)) + e2) = p0;
            *(u32*)((char*)lds + (j0 + 1) * 128 + 16 * (gG ^ ((j0 + 1) & 7)) + e2) = p1;
        }
#pragma unroll
        for (int ii = 0; ii < 2; ++ii) {
            int s = ii * 512 + t;
            int row_ = s >> 3, ch_ = s & 7;
            *(uint4*)((char*)lds + 16384 + row_ * 128 + 16 * (ch_ ^ (row_ & 7))) = rb[ii];
        }
        __syncthreads();
        if (k0 + 64 < 512) {
            const int c0n = (k0 + 64) >> 2;
            const float* xp = x + (((long)(b * Cc + c0n + cc)) * Hh + (2 * i + dy)) * Wf;
#pragma unroll
            for (int q = 0; q < 4; ++q) {
                int col = (half * 4 + q) * 32 + colblk * 4;
                xv[q] = *(const float4*)(xp + col);
            }
#pragma unroll
            for (int ii = 0; ii < 2; ++ii) {
                int s = ii * 512 + t;
                rb[ii] = *(const uint4*)(Wt + (long)(s >> 3) * 512 + (k0 + 64) + (s & 7) * 8);
            }
        }
#pragma unroll
        for (int ks = 0; ks < 2; ++ks) {
            short8 af[4], bfv[2];
            const int ch = ks * 4 + kq;
#pragma unroll
            for (int mi = 0; mi < 4; ++mi) {
                int row = wr * 64 + mi * 16 + r15;
                af[mi] = *(const short8*)((const char*)lds + row * 128 + 16 * (ch ^ (row & 7)));
            }
#pragma unroll
            for (int ni = 0; ni < 2; ++ni) {
                int row = wc * 32 + ni * 16 + r15;
                bfv[ni] = *(const short8*)((const char*)lds + 16384 + row * 128 + 16 * (ch ^ (row & 7)));
            }
#pragma unroll
            for (int mi = 0; mi < 4; ++mi)
#pragma unroll
                for (int ni = 0; ni < 2; ++ni)
                    acc[mi][ni] = __builtin_amdgcn_mfma_f32_16x16x32_bf16(
                        af[mi], bfv[ni], acc[mi][ni], 0, 0, 0);
        }
    }
    __syncthreads();

#pragma unroll
    for (int mi = 0; mi < 4; ++mi)
#pragma unroll
        for (int ni = 0; ni < 2; ++ni)
#pragma unroll
            for (int r = 0; r < 4; ++r) {
                int row = wr * 64 + mi * 16 + kq * 4 + r;
                int col = wc * 32 + ni * 16 + r15;
                lds[row * 128 + (col ^ ((row & 7) << 3))] = f2bf(acc[mi][ni][r]);
            }
#pragma unroll
    for (int ni = 0; ni < 2; ++ni) {
        float s = 0.f, q2 = 0.f;
#pragma unroll
        for (int mi = 0; mi < 4; ++mi)
#pragma unroll
            for (int r = 0; r < 4; ++r) {
                float v = acc[mi][ni][r];
                s += v; q2 += v * v;
            }
        s += __shfl_down(s, 32); s += __shfl_down(s, 16);
        q2 += __shfl_down(q2, 32); q2 += __shfl_down(q2, 16);
        if (lane < 16) {
            int col = wc * 32 + ni * 16 + r15;
            atomicAdd(&sblk[col], s);
            atomicAdd(&qblk[col], q2);
        }
    }
    __syncthreads();
    {
        u16* Cb = Cout + (long)b * HW2 * 128;
        int row = t >> 2, quarter = (t & 3) * 32;
        int sx = (row & 7) << 3;
        long gbase = (long)(i * 128 + row) * 128;
#pragma unroll
        for (int q = 0; q < 4; ++q) {
            int c = quarter + q * 8;
            *(uint4*)(Cb + gbase + c) = *(const uint4*)(lds + row * 128 + (c ^ sx));
        }
    }
    if (t < 128) {
        atomicAdd(statS + (long)t * 16, sblk[t]);
        atomicAdd(statQ + (long)t * 16, qblk[t]);
    }
}

// ---- depthwise 3x3 NHWC, 4-row tile, fused BN1+gelu + LN stats ----
__global__ __launch_bounds__(256) void k_dwconv(const u16* __restrict__ xin,
                                                u16* __restrict__ y,
                                                const float* __restrict__ w,
                                                const float* __restrict__ bias,
                                                const float* __restrict__ bnS,
                                                const float* __restrict__ bnQ,
                                                const float* __restrict__ g1,
                                                const float* __restrict__ b1,
                                                float* __restrict__ lnS,
                                                float* __restrict__ lnQ) {
    __shared__ float wl2[1152];
    __shared__ float sA[128], sB[128];
    __shared__ __align__(16) u16 tile[108 * 136];
    const int t = threadIdx.x;
    if (t < 128) {
        const float invN = 1.0f / 131072.0f;
        float mu = bnS[(long)t * 16] * invN;
        float var = bnQ[(long)t * 16] * invN - mu * mu;
        float rs = rsqrtf(var + 1e-5f);
        float sc = rs * g1[t];
        sA[t] = sc;
        sB[t] = b1[t] - mu * sc;
    }
    for (int idx = t; idx < 1152; idx += 256) {
        int c = idx / 9, tap = idx - c * 9;
        wl2[tap * 128 + (c & 7) * 16 + (c >> 3)] = w[idx];
    }
    __syncthreads();
    const int jbase = blockIdx.x * 16, i0 = blockIdx.y * 4, b = blockIdx.z;
    const u16* xb = xin + (long)b * HW2 * 128;
    {
        int seg = t & 15, slot0 = t >> 4;
#pragma unroll
        for (int pass = 0; pass < 7; ++pass) {
            int slot = pass * 16 + slot0;
            if (slot < 108) {
                int r = slot / 18, p = slot - r * 18;
                int row = i0 - 1 + r, col = jbase - 1 + p;
                bool inb = (row >= 0) & (row < H2) & (col >= 0) & (col < W2);
                uint4 raw = inb ? *(const uint4*)(xb + ((long)row * W2 + col) * 128 + seg * 8)
                                : make_uint4(0u, 0u, 0u, 0u);
                const u16* pv = (const u16*)&raw;
                uint4 outv; u16* ov = (u16*)&outv;
#pragma unroll
                for (int u = 0; u < 8; ++u) {
                    int c = seg * 8 + u;
                    float v = inb ? gelu_f(bf2f(pv[u]) * sA[c] + sB[c]) : 0.f;
                    ov[u] = f2bf(v);
                }
                *(uint4*)(tile + slot * 136 + seg * 8) = outv;
            }
        }
    }
    __syncthreads();
    const int cg = t & 15, jj = t >> 4;
    float s = 0.f, q2 = 0.f;
    float bi[8];
#pragma unroll
    for (int u = 0; u < 8; ++u) bi[u] = bias[cg * 8 + u];
#pragma unroll
    for (int dr = 0; dr < 4; ++dr) {
        float acc[8];
#pragma unroll
        for (int u = 0; u < 8; ++u) acc[u] = bi[u];
#pragma unroll
        for (int r = 0; r < 3; ++r)
#pragma unroll
            for (int dj = 0; dj < 3; ++dj) {
                short8 vv = *(const short8*)(tile + ((dr + r) * 18 + jj + dj) * 136 + cg * 8);
                const int tap = r * 3 + dj;
#pragma unroll
                for (int u = 0; u < 8; ++u)
                    acc[u] = fmaf(bf2f((u16)vv[u]), wl2[tap * 128 + u * 16 + cg], acc[u]);
            }
        uint4 outv; u16* ov = (u16*)&outv;
#pragma unroll
        for (int u = 0; u < 8; ++u) {
            ov[u] = f2bf(acc[u]);
            s += acc[u]; q2 += acc[u] * acc[u];
        }
        *(uint4*)(y + ((long)b * HW2 + (long)(i0 + dr) * W2 + jbase + jj) * 128 + cg * 8) = outv;
    }
#pragma unroll
    for (int off = 32; off; off >>= 1) {
        s += __shfl_down(s, off);
        q2 += __shfl_down(q2, off);
    }
    __shared__ float r1[4], r2[4];
    if ((t & 63) == 0) { r1[t >> 6] = s; r2[t >> 6] = q2; }
    __syncthreads();
    if (t == 0) {
        int slot = (blockIdx.y * 8 + blockIdx.x) & 63;
        atomicAdd(lnS + ((long)b * 64 + slot) * 16, r1[0] + r1[1] + r1[2] + r1[3]);
        atomicAdd(lnQ + ((long)b * 64 + slot) * 16, r2[0] + r2[1] + r2[2] + r2[3]);
    }
}

// ---- fused MLP (512 thr): pw1 -> pw2; resA + W2 loads hoisted to prologue ----
__global__ __launch_bounds__(512) void k_mlp(const u16* __restrict__ D,
                                             const u16* __restrict__ Wp1,
                                             const u16* __restrict__ Wp2,
                                             const float* __restrict__ b1p,
                                             const float* __restrict__ b2p,
                                             const u16* __restrict__ resA,
                                             u16* __restrict__ Yout,
                                             const float* __restrict__ lnS,
                                             const float* __restrict__ lnQ,
                                             const float* __restrict__ wbv,
                                             const float* __restrict__ wgs,
                                             const float* __restrict__ bnS,
                                             const float* __restrict__ bnQ,
                                             const float* __restrict__ g1,
                                             const float* __restrict__ b1v) {
    __shared__ __align__(16) u16 lA[16384];
    __shared__ __align__(16) u16 lB[16384];
    __shared__ float s1[128], s2[128], sA[128], sB[128], lnred[2];
    const int t = threadIdx.x;
    const int lane = t & 63, w = t >> 6, wr = w & 1, wc = w >> 1;
    const int r15 = lane & 15, kq = lane >> 4;
    const int b = blockIdx.z, m0 = blockIdx.y * 128;

    if (t < 64) {
        float s = lnS[((long)b * 64 + t) * 16];
        float q = lnQ[((long)b * 64 + t) * 16];
#pragma unroll
        for (int off = 32; off; off >>= 1) {
            s += __shfl_down(s, off);
            q += __shfl_down(q, off);
        }
        if (t == 0) { lnred[0] = s; lnred[1] = q; }
    }
    __syncthreads();
    const float invN = 1.0f / 2097152.0f;
    float mu = lnred[0] * invN;
    float var = lnred[1] * invN - mu * mu;
    const float rs = rsqrtf(var + 1e-5f);
    if (t < 128) {
        s1[t] = b1p[t] + wbv[t] - mu * rs * wgs[t];
        s2[t] = b2p[t];
        const float invN1 = 1.0f / 131072.0f;
        float mu1 = bnS[(long)t * 16] * invN1;
        float var1 = bnQ[(long)t * 16] * invN1 - mu1 * mu1;
        float rs1 = rsqrtf(var1 + 1e-5f);
        float sc1 = rs1 * g1[t];
        sA[t] = sc1;
        sB[t] = b1v[t] - mu1 * sc1;
    }

    const u16* Ab = D + ((long)b * HW2 + m0) * 128;
    const u16* Ra = resA + ((long)b * HW2 + m0) * 128;
    const int erow = t >> 2, equarter = (t & 3) * 32;   // epilogue mapping
    uint4 ga[4], gb[4], gr[4];
#pragma unroll
    for (int i = 0; i < 4; ++i) {
        int s = i * 512 + t, row = s >> 4, seg = s & 15;
        ga[i] = *(const uint4*)(Ab + (long)row * 128 + seg * 8);
        gb[i] = *(const uint4*)(Wp1 + (long)row * 128 + seg * 8);
    }
    // hoisted residual load (consumed only in epilogue; hides under both GEMMs)
#pragma unroll
    for (int q = 0; q < 4; ++q)
        gr[q] = *(const uint4*)(Ra + (long)erow * 128 + equarter + q * 8);
#pragma unroll
    for (int i = 0; i < 4; ++i) {
        int s = i * 512 + t, row = s >> 4, seg = s & 15;
        int off = (seg >> 3) * 16384 + row * 128 + 16 * ((seg & 7) ^ (row & 7));
        *(uint4*)((char*)lA + off) = ga[i];
        *(uint4*)((char*)lB + off) = gb[i];
    }
    __syncthreads();
    // prefetch pw2 weights EARLY (hides under GEMM1 MFMA)
#pragma unroll
    for (int i = 0; i < 4; ++i) {
        int s = i * 512 + t, row = s >> 4, seg = s & 15;
        gb[i] = *(const uint4*)(Wp2 + (long)row * 128 + seg * 8);
    }

    f32x4 acc[4][2];
#pragma unroll
    for (int i = 0; i < 4; ++i)
#pragma unroll
        for (int j = 0; j < 2; ++j) acc[i][j] = (f32x4){0.f, 0.f, 0.f, 0.f};
#pragma unroll
    for (int chunk = 0; chunk < 2; ++chunk)
#pragma unroll
        for (int ks = 0; ks < 2; ++ks) {
            const int ch = ks * 4 + kq;
            short8 af[4], bfv[2];
#pragma unroll
            for (int mi = 0; mi < 4; ++mi) {
                int row = wr * 64 + mi * 16 + r15;
                af[mi] = *(const short8*)((const char*)lA + chunk * 16384 +
                                          row * 128 + 16 * (ch ^ (row & 7)));
            }
#pragma unroll
            for (int ni = 0; ni < 2; ++ni) {
                int row = wc * 32 + ni * 16 + r15;
                bfv[ni] = *(const short8*)((const char*)lB + chunk * 16384 +
                                           row * 128 + 16 * (ch ^ (row & 7)));
            }
#pragma unroll
            for (int mi = 0; mi < 4; ++mi)
#pragma unroll
                for (int ni = 0; ni < 2; ++ni)
                    acc[mi][ni] = __builtin_amdgcn_mfma_f32_16x16x32_bf16(
                        af[mi], bfv[ni], acc[mi][ni], 0, 0, 0);
        }
    __syncthreads();

    // bounce1: gelu(rs*acc + s1[ch]) -> lA in GEMM-A k-major layout (k = ch)
#pragma unroll
    for (int mi = 0; mi < 4; ++mi)
#pragma unroll
        for (int ni = 0; ni < 2; ++ni)
#pragma unroll
            for (int r = 0; r < 4; ++r) {
                int row = wr * 64 + mi * 16 + kq * 4 + r;
                int col = wc * 32 + ni * 16 + r15;
                float v = gelu_f(rs * acc[mi][ni][r] + s1[col]);
                lA[(col >> 6) * 8192 + row * 64 +
                   8 * (((col >> 3) & 7) ^ (row & 7)) + (col & 7)] = f2bf(v);
            }
#pragma unroll
    for (int i = 0; i < 4; ++i) {
        int s = i * 512 + t, row = s >> 4, seg = s & 15;
        int off = (seg >> 3) * 16384 + row * 128 + 16 * ((seg & 7) ^ (row & 7));
        *(uint4*)((char*)lB + off) = gb[i];
    }
    __syncthreads();

    // GEMM2
#pragma unroll
    for (int i = 0; i < 4; ++i)
#pragma unroll
        for (int j = 0; j < 2; ++j) acc[i][j] = (f32x4){0.f, 0.f, 0.f, 0.f};
#pragma unroll
    for (int chunk = 0; chunk < 2; ++chunk)
#pragma unroll
        for (int ks = 0; ks < 2; ++ks) {
            const int ch = ks * 4 + kq;
            short8 af[4], bfv[2];
#pragma unroll
            for (int mi = 0; mi < 4; ++mi) {
                int row = wr * 64 + mi * 16 + r15;
                af[mi] = *(const short8*)((const char*)lA + chunk * 16384 +
                                          row * 128 + 16 * (ch ^ (row & 7)));
            }
#pragma unroll
            for (int ni = 0; ni < 2; ++ni) {
                int row = wc * 32 + ni * 16 + r15;
                bfv[ni] = *(const short8*)((const char*)lB + chunk * 16384 +
                                           row * 128 + 16 * (ch ^ (row & 7)));
            }
#pragma unroll
            for (int mi = 0; mi < 4; ++mi)
#pragma unroll
                for (int ni = 0; ni < 2; ++ni)
                    acc[mi][ni] = __builtin_amdgcn_mfma_f32_16x16x32_bf16(
                        af[mi], bfv[ni], acc[mi][ni], 0, 0, 0);
        }
    __syncthreads();

#pragma unroll
    for (int mi = 0; mi < 4; ++mi)
#pragma unroll
        for (int ni = 0; ni < 2; ++ni)
#pragma unroll
            for (int r = 0; r < 4; ++r) {
                int row = wr * 64 + mi * 16 + kq * 4 + r;
                int col = wc * 32 + ni * 16 + r15;
                lA[row * 128 + (col ^ ((row & 7) << 3))] = f2bf(acc[mi][ni][r]);
            }
    __syncthreads();

    u16* Cb = Yout + ((long)b * HW2 + m0) * 128;
    {
        int sx = (erow & 7) << 3;
#pragma unroll
        for (int q = 0; q < 4; ++q) {
            int c = equarter + q * 8;
            uint4 raw = *(const uint4*)(lA + erow * 128 + (c ^ sx));
            u16* pv = (u16*)&raw;
            const u16* rv = (const u16*)&gr[q];
#pragma unroll
            for (int u = 0; u < 8; ++u) {
                float hres = gelu_f(bf2f(rv[u]) * sA[c + u] + sB[c + u]);
                pv[u] = f2bf(bf2f(pv[u]) + s2[c + u] + hres);
            }
            *(uint4*)(Cb + (long)erow * 128 + c) = raw;
        }
    }
}

// ---- second moment partials: 256 blocks x 512 px, pipelined Y loads ----
__global__ __launch_bounds__(256) void k_moment(const u16* __restrict__ Y,
                                                float* __restrict__ M2p,
                                                float* __restrict__ csum) {
    __shared__ __align__(16) u16 T[8192];
    __shared__ float cred[16][16][8];
    const int t = threadIdx.x;
    const int lane = t & 63, w = t >> 6, wr = w >> 1, wc = w & 1;
    const int r15 = lane & 15, kq = lane >> 4;
    const long px0 = (long)blockIdx.x * 512;
    const int px_ = (t * 4) >> 4, ch8_ = ((t * 4) & 12) * 8;   // unused helper
    (void)px_; (void)ch8_;
    float cs[8] = {};

    f32x4 acc[4][4];
#pragma unroll
    for (int i = 0; i < 4; ++i)
#pragma unroll
        for (int j = 0; j < 4; ++j) acc[i][j] = (f32x4){0.f, 0.f, 0.f, 0.f};

    uint4 rv[4];
#pragma unroll
    for (int i = 0; i < 4; ++i) {
        int s = i * 256 + t;
        int px = s >> 4, ch8 = (s & 15) * 8;
        rv[i] = *(const uint4*)(Y + (px0 + px) * 128 + ch8);
    }
    for (int it = 0; it < 8; ++it) {
        // col-sums from current registers
#pragma unroll
        for (int i = 0; i < 4; ++i) {
            const u16* pv = (const u16*)&rv[i];
#pragma unroll
            for (int u = 0; u < 8; ++u) cs[u] += bf2f(pv[u]);
        }
        __syncthreads();
#pragma unroll
        for (int i = 0; i < 4; ++i) {
            int s = i * 256 + t;
            int px = s >> 4, ch8 = (s & 15) * 8;
            const u16* pv = (const u16*)&rv[i];
#pragma unroll
            for (int u = 0; u < 8; ++u) {
                int row = ch8 + u;
                T[row * 64 + 8 * ((px >> 3) ^ (row & 7)) + (px & 7)] = pv[u];
            }
        }
        __syncthreads();
        // prefetch next iteration's Y while MFMA runs
        if (it + 1 < 8) {
#pragma unroll
            for (int i = 0; i < 4; ++i) {
                int s = i * 256 + t;
                int px = s >> 4, ch8 = (s & 15) * 8;
                rv[i] = *(const uint4*)(Y + (px0 + (it + 1) * 64 + px) * 128 + ch8);
            }
        }
#pragma unroll
        for (int ks = 0; ks < 2; ++ks) {
            const int ch = ks * 4 + kq;
            short8 af[4], bfv[4];
#pragma unroll
            for (int mi = 0; mi < 4; ++mi) {
                int row = wr * 64 + mi * 16 + r15;
                af[mi] = *(const short8*)(T + row * 64 + 8 * (ch ^ (row & 7)));
            }
#pragma unroll
            for (int ni = 0; ni < 4; ++ni) {
                int row = wc * 64 + ni * 16 + r15;
                bfv[ni] = *(const short8*)(T + row * 64 + 8 * (ch ^ (row & 7)));
            }
#pragma unroll
            for (int mi = 0; mi < 4; ++mi)
#pragma unroll
                for (int ni = 0; ni < 4; ++ni)
                    acc[mi][ni] = __builtin_amdgcn_mfma_f32_16x16x32_bf16(
                        af[mi], bfv[ni], acc[mi][ni], 0, 0, 0);
        }
    }
    {
        int g = t & 15, m = t >> 4;
#pragma unroll
        for (int u = 0; u < 8; ++u) cred[m][g][u] = cs[u];
    }
    __syncthreads();
    if (t < 128) {
        float s = 0.f;
#pragma unroll
        for (int m = 0; m < 16; ++m) s += cred[m][t >> 3][t & 7];
        atomicAdd(csum + (long)t * 16, s);
    }
    float* Mb = M2p + (long)blockIdx.x * 16384;
#pragma unroll
    for (int mi = 0; mi < 4; ++mi)
#pragma unroll
        for (int ni = 0; ni < 4; ++ni)
#pragma unroll
            for (int r = 0; r < 4; ++r) {
                int row = wr * 64 + mi * 16 + kq * 4 + r;
                int col = wc * 64 + ni * 16 + r15;
                Mb[row * 128 + col] = acc[mi][ni][r];
            }
}

// ---- reduce 256 M2 partials -> M2 dense ----
__global__ __launch_bounds__(256) void k_m2red(const float* __restrict__ M2p,
                                               float* __restrict__ M2) {
    int e = blockIdx.x * 256 + threadIdx.x;
    float s = 0.f;
    for (int p = 0; p < 256; ++p) s += M2p[(long)p * 16384 + e];
    M2[e] = s;
}

// ---- combine: per-out-channel BN2 scale/shift ----
__global__ __launch_bounds__(128) void k_statcomb(const float* __restrict__ w_c2,
                                                  const float* __restrict__ M2,
                                                  const float* __restrict__ csum,
                                                  const float* __restrict__ g,
                                                  const float* __restrict__ bb,
                                                  float* __restrict__ scsh) {
    __shared__ float wl[128];
    __shared__ float red[2][2];
    const int o = blockIdx.x, c = threadIdx.x;
    wl[c] = w_c2[o * 128 + c];
    __syncthreads();
    const float* m2r = M2 + c * 128;
    float tmp = 0.f;
#pragma unroll
    for (int c2 = 0; c2 < 128; c2 += 4) {
        float4 m = *(const float4*)(m2r + c2);
        tmp += m.x * wl[c2] + m.y * wl[c2 + 1] + m.z * wl[c2 + 2] + m.w * wl[c2 + 3];
    }
    float s2p = wl[c] * tmp;
    float mup = wl[c] * csum[(long)c * 16];
#pragma unroll
    for (int off = 32; off; off >>= 1) {
        s2p += __shfl_down(s2p, off);
        mup += __shfl_down(mup, off);
    }
    if ((c & 63) == 0) { red[0][c >> 6] = s2p; red[1][c >> 6] = mup; }
    __syncthreads();
    if (c == 0) {
        float s2 = (red[0][0] + red[0][1]) / NPIX;
        float mu = (red[1][0] + red[1][1]) / NPIX;
        float var = s2 - mu * mu;
        float rs = rsqrtf(var + 1e-5f);
        float sc = g[o] * rs;
        scsh[o] = sc;
        scsh[512 + o] = bb[o] - mu * sc;
    }
}

// ---- conv2 + BN2 + GELU + IDWT; weight prefetch hoisted before MFMA ----
__global__ __launch_bounds__(512) void k_conv2_idwt(const u16* __restrict__ Y,
                                                    const u16* __restrict__ Wc,
                                                    const float* __restrict__ scsh,
                                                    float* __restrict__ out) {
    __shared__ __align__(16) u16 lA[16384];
    __shared__ __align__(16) u16 lB[8192];
    __shared__ float sparam[1024];
    const int t = threadIdx.x;
    const int lane = t & 63, w = t >> 6, wr = w & 1, wc = w >> 1;
    const int r15 = lane & 15, kq = lane >> 4;
    const int b = blockIdx.y, n0 = blockIdx.x;
#pragma unroll
    for (int u = 0; u < 2; ++u) sparam[t + u * 512] = scsh[t + u * 512];

    const u16* Yb = Y + ((long)b * HW2 + (long)n0 * 64) * 128;
    uint4 rb2[2], ra4[4];
#pragma unroll
    for (int i = 0; i < 2; ++i) {
        int s = i * 512 + t, row = s >> 4, seg = s & 15;
        rb2[i] = *(const uint4*)(Yb + (long)row * 128 + seg * 8);
    }
#define GLOADA(q)                                                                \
    {                                                                            \
        _Pragma("unroll")                                                        \
        for (int i = 0; i < 4; ++i) {                                            \
            int s = i * 512 + t, row = s >> 4, seg = s & 15;                     \
            ra4[i] = *(const uint4*)(Wc + (long)((q) * 128 + row) * 128 + seg * 8); \
        }                                                                        \
    }
#define LWRITEA()                                                                \
    {                                                                            \
        _Pragma("unroll")                                                        \
        for (int i = 0; i < 4; ++i) {                                            \
            int s = i * 512 + t, row = s >> 4, seg = s & 15;                     \
            *(uint4*)((char*)lA + (seg >> 3) * 16384 + row * 128 +               \
                      16 * ((seg & 7) ^ (row & 7))) = ra4[i];                    \
        }                                                                        \
    }
    GLOADA(0)
#pragma unroll
    for (int i = 0; i < 2; ++i) {
        int s = i * 512 + t, row = s >> 4, seg = s & 15;
        *(uint4*)((char*)lB + (seg >> 3) * 8192 + row * 128 +
                  16 * ((seg & 7) ^ (row & 7))) = rb2[i];
    }
    LWRITEA()
    __syncthreads();

    u32 sbp[4][4][2];
#pragma unroll
    for (int q = 0; q < 4; ++q) {
        if (q < 3) GLOADA(q + 1)
        f32x4 acc[4];
#pragma unroll
        for (int mi = 0; mi < 4; ++mi) acc[mi] = (f32x4){0.f, 0.f, 0.f, 0.f};
#pragma unroll
        for (int chunk = 0; chunk < 2; ++chunk)
#pragma unroll
            for (int ks = 0; ks < 2; ++ks) {
                const int ch = ks * 4 + kq;
                short8 af[4], bfv;
#pragma unroll
                for (int mi = 0; mi < 4; ++mi) {
                    int row = wr * 64 + mi * 16 + r15;
                    af[mi] = *(const short8*)((const char*)lA + chunk * 16384 +
                                              row * 128 + 16 * (ch ^ (row & 7)));
                }
                {
                    int row = wc * 16 + r15;
                    bfv = *(const short8*)((const char*)lB + chunk * 8192 +
                                           row * 128 + 16 * (ch ^ (row & 7)));
                }
#pragma unroll
                for (int mi = 0; mi < 4; ++mi)
                    acc[mi] = __builtin_amdgcn_mfma_f32_16x16x32_bf16(
                        af[mi], bfv, acc[mi], 0, 0, 0);
            }
#pragma unroll
        for (int mi = 0; mi < 4; ++mi)
#pragma unroll
            for (int rp = 0; rp < 2; ++rp) {
                int c0 = q * 128 + wr * 64 + mi * 16 + kq * 4 + rp * 2;
                float v0 = gelu_f(acc[mi][rp * 2] * sparam[c0] + sparam[512 + c0]);
                float v1 = gelu_f(acc[mi][rp * 2 + 1] * sparam[c0 + 1] + sparam[512 + c0 + 1]);
                sbp[q][mi][rp] = (u32)f2bf(v0) | ((u32)f2bf(v1) << 16);
            }
        if (q < 3) {
            __syncthreads();
            LWRITEA()
            __syncthreads();
        }
    }
    const int i = n0 >> 1;
    const int j = (n0 & 1) * 64 + wc * 16 + r15;
#pragma unroll
    for (int mi = 0; mi < 4; ++mi)
#pragma unroll
        for (int rp = 0; rp < 2; ++rp) {
            u32 p0 = sbp[0][mi][rp], p1 = sbp[1][mi][rp];
            u32 p2 = sbp[2][mi][rp], p3 = sbp[3][mi][rp];
#pragma unroll
            for (int e = 0; e < 2; ++e) {
                int c = wr * 64 + mi * 16 + kq * 4 + rp * 2 + e;
                float ll = bf2f(e ? (u16)(p0 >> 16) : (u16)(p0 & 0xFFFF));
                float lh = bf2f(e ? (u16)(p1 >> 16) : (u16)(p1 & 0xFFFF));
                float hl = bf2f(e ? (u16)(p2 >> 16) : (u16)(p2 & 0xFFFF));
                float hh = bf2f(e ? (u16)(p3 >> 16) : (u16)(p3 & 0xFFFF));
                long ob = (((long)(b * Cc + c) * Hh + 2 * i) * Wf + 2 * j);
                union { float2 v; u64 u; } w0, w1;
                w0.v = make_float2((ll + lh + hl + hh) * 0.5f, (ll + lh - hl - hh) * 0.5f);
                w1.v = make_float2((ll - lh + hl - hh) * 0.5f, (ll - lh - hl + hh) * 0.5f);
                __builtin_nontemporal_store(w0.u, (u64*)(out + ob));
                __builtin_nontemporal_store(w1.u, (u64*)(out + ob + Wf));
            }
        }
#undef GLOADA
#undef LWRITEA
}

extern "C" void kernel_launch(void* const* d_in, const int* in_sizes, int n_in,
                              void* d_out, int out_size, void* d_ws, size_t ws_size,
                              hipStream_t stream) {
    const float* x     = (const float*)d_in[0];
    const float* w_c1  = (const float*)d_in[1];
    const float* bn1_g = (const float*)d_in[3];
    const float* bn1_b = (const float*)d_in[4];
    const float* dw_w  = (const float*)d_in[5];
    const float* dw_b  = (const float*)d_in[6];
    const float* gn_g  = (const float*)d_in[7];
    const float* gn_b  = (const float*)d_in[8];
    const float* pw1_w = (const float*)d_in[9];
    const float* pw1_b = (const float*)d_in[10];
    const float* pw2_w = (const float*)d_in[11];
    const float* pw2_b = (const float*)d_in[12];
    const float* w_c2  = (const float*)d_in[13];
    const float* bn2_g = (const float*)d_in[15];
    const float* bn2_b = (const float*)d_in[16];
    float* out = (float*)d_out;

    const size_t n128 = (size_t)Bq * Cc * HW2;
    u16* bufA = (u16*)d_ws;
    u16* bufD = bufA + n128;
    u16* bufY = bufD + n128;
    u16* wb   = bufY + n128;
    float* stats = (float*)(wb + 163840);
    float* M2p = stats + 49152;    // 256 x 16384 f32 partials (16 MB)
    size_t need = (3 * n128 + 163840) * 2 + (49152 + 256 * 16384) * 4;
    if (ws_size < need) return;

    float* bn1_sum = stats;
    float* bn1_sq  = stats + 2048;
    float* ln_sum  = stats + 4096;
    float* ln_sq   = stats + 12288;
    float* csum    = stats + 20480;
    float* M2      = stats + 22528;
    float* scsh    = stats + 38912;
    float* wbv     = stats + 39936;
    float* wgs     = stats + 40064;

    // 0. weights -> bf16 + stats zeroing + LN-fold vectors (block 640)
    k_wconv<<<641, 256, 0, stream>>>(w_c1, pw1_w, pw2_w, w_c2, gn_g, gn_b,
                                     wb, wbv, wgs, stats);

    // 1. fused DWT + conv1 + BN1 stats
    k_conv1<<<dim3(1, 128, 8), 512, 0, stream>>>(x, wb, bufA, bn1_sum, bn1_sq);

    // 2. depthwise 3x3, 4-row tiles, fused BN1+gelu on load + LN stats
    k_dwconv<<<dim3(8, 32, 8), 256, 0, stream>>>(bufA, bufD, dw_w, dw_b,
                                                 bn1_sum, bn1_sq, bn1_g, bn1_b,
                                                 ln_sum, ln_sq);

    // 3. fused MLP (512 thr): pw1 -> pw2; residual load hoisted
    k_mlp<<<dim3(1, 128, 8), 512, 0, stream>>>(
        bufD, wb + 65536, wb + 81920, pw1_b, pw2_b, bufA, bufY,
        ln_sum, ln_sq, wbv, wgs, bn1_sum, bn1_sq, bn1_g, bn1_b);

    // 4. BN2 stats: per-block M2 partials (pipelined loads) + reduce + combine
    k_moment<<<256, 256, 0, stream>>>(bufY, M2p, csum);
    k_m2red<<<64, 256, 0, stream>>>(M2p, M2);
    k_statcomb<<<512, 128, 0, stream>>>(w_c2, M2, csum, bn2_g, bn2_b, scsh);

    // 5. conv2 + BN2 + gelu + IDWT -> out (NT stores, hoisted prefetch)
    k_conv2_idwt<<<dim3(256, 8), 512, 0, stream>>>(bufY, wb + 98304, scsh, out);
}

// Round 16
// 382.475 us; speedup vs baseline: 1.0314x; 1.0314x over previous
//
#include <hip/hip_runtime.h>
#include <hip/hip_bf16.h>

typedef unsigned short u16;
typedef unsigned int u32;
typedef unsigned long long u64;
typedef __attribute__((ext_vector_type(8))) short short8;
typedef __attribute__((ext_vector_type(4))) float f32x4;

#define Bq 8
#define Cc 128
#define C4 512
#define Hh 256
#define Wf 256
#define H2 128
#define W2 128
#define HW2 16384
#define NPIX 131072.0f

__device__ __forceinline__ float gelu_f(float x) {
    float u = 1.5957691216057308f * (x + 0.044715f * x * x * x);
    float t = 1.0f - 2.0f / (__expf(u) + 1.0f);
    return 0.5f * x * (1.0f + t);
}
__device__ __forceinline__ float bf2f(u16 u) {
    union { float f; u32 i; } v; v.i = ((u32)u) << 16; return v.f;
}
__device__ __forceinline__ u16 f2bf(float f) {
    union { float f; u32 i; } v; v.f = f;
    u32 r = v.i + 0x7FFFu + ((v.i >> 16) & 1u);
    return (u16)(r >> 16);
}

// ---- weights f32 -> bf16; block 640: zero stats + LN-fold vectors ----
__global__ __launch_bounds__(256) void k_wconv(const float* __restrict__ w_c1,
                                               const float* __restrict__ pw1,
                                               const float* __restrict__ pw2,
                                               const float* __restrict__ w_c2,
                                               const float* __restrict__ gn_g,
                                               const float* __restrict__ gn_b,
                                               u16* __restrict__ wb,
                                               float* __restrict__ wbv,
                                               float* __restrict__ wgs,
                                               float* __restrict__ stats0) {
    if (blockIdx.x == 640) {
        for (int e = threadIdx.x; e < 22528; e += 256) stats0[e] = 0.f;
        int o = threadIdx.x;
        if (o < 128) {
            float a = 0.f, bv = 0.f;
            for (int c = 0; c < 128; ++c) {
                float w_ = pw1[o * 128 + c];
                a += w_ * gn_g[c];
                bv += w_ * gn_b[c];
            }
            wgs[o] = a;
            wbv[o] = bv;
        }
        return;
    }
    int i = blockIdx.x * 256 + threadIdx.x;   // 0..163839
    float v;
    if (i < 65536) {
        int o = i >> 9, kn = i & 511;
        int c = kn >> 2, dy = (kn >> 1) & 1, dx = kn & 1;
        float sdy = dy ? -1.f : 1.f, sdx = dx ? -1.f : 1.f;
        const float* wr = w_c1 + o * 512 + c;
        v = 0.5f * (wr[0] + sdy * wr[128] + sdx * wr[256] + sdy * sdx * wr[384]);
    } else if (i < 81920) v = pw1[i - 65536] * gn_g[(i - 65536) & 127];
    else if (i < 98304) v = pw2[i - 81920];
    else v = w_c2[i - 98304];
    wb[i] = f2bf(v);
}

// ---- fused DWT+conv1+BN1-stats: reads x f32 NCHW directly (512 thr) ----
__global__ __launch_bounds__(512) void k_conv1(const float* __restrict__ x,
                                               const u16* __restrict__ Wt,
                                               u16* __restrict__ Cout,
                                               float* __restrict__ statS,
                                               float* __restrict__ statQ) {
    __shared__ __align__(16) u16 lds[16384];
    __shared__ float sblk[128], qblk[128];
    const int t = threadIdx.x;
    const int lane = t & 63, w = t >> 6, wr = w & 1, wc = w >> 1;
    const int b = blockIdx.z, i = blockIdx.y;
    if (t < 128) { sblk[t] = 0.f; qblk[t] = 0.f; }

    const int r15 = lane & 15, kq = lane >> 4;
    const int half = t >> 8;
    const int colblk = t & 7, cc = (t >> 3) & 15, dy = (t >> 7) & 1;
    const int kbase = cc * 4 + dy * 2;
    const int gG = kbase >> 3, e2 = (kbase & 7) * 2;

    float4 xv[4];
    uint4 rb[2];
    {
        const float* xp = x + (((long)(b * Cc + cc)) * Hh + (2 * i + dy)) * Wf;
#pragma unroll
        for (int q = 0; q < 4; ++q) {
            int col = (half * 4 + q) * 32 + colblk * 4;
            xv[q] = *(const float4*)(xp + col);
        }
#pragma unroll
        for (int ii = 0; ii < 2; ++ii) {
            int s = ii * 512 + t;
            rb[ii] = *(const uint4*)(Wt + (long)(s >> 3) * 512 + (s & 7) * 8);
        }
    }

    f32x4 acc[4][2];
#pragma unroll
    for (int a2 = 0; a2 < 4; ++a2)
#pragma unroll
        for (int j2 = 0; j2 < 2; ++j2) acc[a2][j2] = (f32x4){0.f, 0.f, 0.f, 0.f};

    for (int k0 = 0; k0 < 512; k0 += 64) {
        __syncthreads();
#pragma unroll
        for (int q = 0; q < 4; ++q) {
            int col = (half * 4 + q) * 32 + colblk * 4;
            int j0 = col >> 1;
            u32 p0 = (u32)f2bf(xv[q].x) | ((u32)f2bf(xv[q].y) << 16);
            u32 p1 = (u32)f2bf(xv[q].z) | ((u32)f2bf(xv[q].w) << 16);
            *(u32*)((char*)lds + j0 * 128 + 16 * (gG ^ (j0 & 7)) + e2) = p0;
            *(u32*)((char*)lds + (j0 + 1) * 128 + 16 * (gG ^ ((j0 + 1) & 7)) + e2) = p1;
        }
#pragma unroll
        for (int ii = 0; ii < 2; ++ii) {
            int s = ii * 512 + t;
            int row_ = s >> 3, ch_ = s & 7;
            *(uint4*)((char*)lds + 16384 + row_ * 128 + 16 * (ch_ ^ (row_ & 7))) = rb[ii];
        }
        __syncthreads();
        if (k0 + 64 < 512) {
            const int c0n = (k0 + 64) >> 2;
            const float* xp = x + (((long)(b * Cc + c0n + cc)) * Hh + (2 * i + dy)) * Wf;
#pragma unroll
            for (int q = 0; q < 4; ++q) {
                int col = (half * 4 + q) * 32 + colblk * 4;
                xv[q] = *(const float4*)(xp + col);
            }
#pragma unroll
            for (int ii = 0; ii < 2; ++ii) {
                int s = ii * 512 + t;
                rb[ii] = *(const uint4*)(Wt + (long)(s >> 3) * 512 + (k0 + 64) + (s & 7) * 8);
            }
        }
#pragma unroll
        for (int ks = 0; ks < 2; ++ks) {
            short8 af[4], bfv[2];
            const int ch = ks * 4 + kq;
#pragma unroll
            for (int mi = 0; mi < 4; ++mi) {
                int row = wr * 64 + mi * 16 + r15;
                af[mi] = *(const short8*)((const char*)lds + row * 128 + 16 * (ch ^ (row & 7)));
            }
#pragma unroll
            for (int ni = 0; ni < 2; ++ni) {
                int row = wc * 32 + ni * 16 + r15;
                bfv[ni] = *(const short8*)((const char*)lds + 16384 + row * 128 + 16 * (ch ^ (row & 7)));
            }
#pragma unroll
            for (int mi = 0; mi < 4; ++mi)
#pragma unroll
                for (int ni = 0; ni < 2; ++ni)
                    acc[mi][ni] = __builtin_amdgcn_mfma_f32_16x16x32_bf16(
                        af[mi], bfv[ni], acc[mi][ni], 0, 0, 0);
        }
    }
    __syncthreads();

#pragma unroll
    for (int mi = 0; mi < 4; ++mi)
#pragma unroll
        for (int ni = 0; ni < 2; ++ni)
#pragma unroll
            for (int r = 0; r < 4; ++r) {
                int row = wr * 64 + mi * 16 + kq * 4 + r;
                int col = wc * 32 + ni * 16 + r15;
                lds[row * 128 + (col ^ ((row & 7) << 3))] = f2bf(acc[mi][ni][r]);
            }
#pragma unroll
    for (int ni = 0; ni < 2; ++ni) {
        float s = 0.f, q2 = 0.f;
#pragma unroll
        for (int mi = 0; mi < 4; ++mi)
#pragma unroll
            for (int r = 0; r < 4; ++r) {
                float v = acc[mi][ni][r];
                s += v; q2 += v * v;
            }
        s += __shfl_down(s, 32); s += __shfl_down(s, 16);
        q2 += __shfl_down(q2, 32); q2 += __shfl_down(q2, 16);
        if (lane < 16) {
            int col = wc * 32 + ni * 16 + r15;
            atomicAdd(&sblk[col], s);
            atomicAdd(&qblk[col], q2);
        }
    }
    __syncthreads();
    {
        u16* Cb = Cout + (long)b * HW2 * 128;
        int row = t >> 2, quarter = (t & 3) * 32;
        int sx = (row & 7) << 3;
        long gbase = (long)(i * 128 + row) * 128;
#pragma unroll
        for (int q = 0; q < 4; ++q) {
            int c = quarter + q * 8;
            *(uint4*)(Cb + gbase + c) = *(const uint4*)(lds + row * 128 + (c ^ sx));
        }
    }
    if (t < 128) {
        atomicAdd(statS + (long)t * 16, sblk[t]);
        atomicAdd(statQ + (long)t * 16, qblk[t]);
    }
}

// ---- depthwise 3x3 NHWC, 4-row tile, fused BN1+gelu + LN stats ----
__global__ __launch_bounds__(256) void k_dwconv(const u16* __restrict__ xin,
                                                u16* __restrict__ y,
                                                const float* __restrict__ w,
                                                const float* __restrict__ bias,
                                                const float* __restrict__ bnS,
                                                const float* __restrict__ bnQ,
                                                const float* __restrict__ g1,
                                                const float* __restrict__ b1,
                                                float* __restrict__ lnS,
                                                float* __restrict__ lnQ) {
    __shared__ float wl2[1152];
    __shared__ float sA[128], sB[128];
    __shared__ __align__(16) u16 tile[108 * 136];
    const int t = threadIdx.x;
    if (t < 128) {
        const float invN = 1.0f / 131072.0f;
        float mu = bnS[(long)t * 16] * invN;
        float var = bnQ[(long)t * 16] * invN - mu * mu;
        float rs = rsqrtf(var + 1e-5f);
        float sc = rs * g1[t];
        sA[t] = sc;
        sB[t] = b1[t] - mu * sc;
    }
    for (int idx = t; idx < 1152; idx += 256) {
        int c = idx / 9, tap = idx - c * 9;
        wl2[tap * 128 + (c & 7) * 16 + (c >> 3)] = w[idx];
    }
    __syncthreads();
    const int jbase = blockIdx.x * 16, i0 = blockIdx.y * 4, b = blockIdx.z;
    const u16* xb = xin + (long)b * HW2 * 128;
    {
        int seg = t & 15, slot0 = t >> 4;
#pragma unroll
        for (int pass = 0; pass < 7; ++pass) {
            int slot = pass * 16 + slot0;
            if (slot < 108) {
                int r = slot / 18, p = slot - r * 18;
                int row = i0 - 1 + r, col = jbase - 1 + p;
                bool inb = (row >= 0) & (row < H2) & (col >= 0) & (col < W2);
                uint4 raw = inb ? *(const uint4*)(xb + ((long)row * W2 + col) * 128 + seg * 8)
                                : make_uint4(0u, 0u, 0u, 0u);
                const u16* pv = (const u16*)&raw;
                uint4 outv; u16* ov = (u16*)&outv;
#pragma unroll
                for (int u = 0; u < 8; ++u) {
                    int c = seg * 8 + u;
                    float v = inb ? gelu_f(bf2f(pv[u]) * sA[c] + sB[c]) : 0.f;
                    ov[u] = f2bf(v);
                }
                *(uint4*)(tile + slot * 136 + seg * 8) = outv;
            }
        }
    }
    __syncthreads();
    const int cg = t & 15, jj = t >> 4;
    float s = 0.f, q2 = 0.f;
    float bi[8];
#pragma unroll
    for (int u = 0; u < 8; ++u) bi[u] = bias[cg * 8 + u];
#pragma unroll
    for (int dr = 0; dr < 4; ++dr) {
        float acc[8];
#pragma unroll
        for (int u = 0; u < 8; ++u) acc[u] = bi[u];
#pragma unroll
        for (int r = 0; r < 3; ++r)
#pragma unroll
            for (int dj = 0; dj < 3; ++dj) {
                short8 vv = *(const short8*)(tile + ((dr + r) * 18 + jj + dj) * 136 + cg * 8);
                const int tap = r * 3 + dj;
#pragma unroll
                for (int u = 0; u < 8; ++u)
                    acc[u] = fmaf(bf2f((u16)vv[u]), wl2[tap * 128 + u * 16 + cg], acc[u]);
            }
        uint4 outv; u16* ov = (u16*)&outv;
#pragma unroll
        for (int u = 0; u < 8; ++u) {
            ov[u] = f2bf(acc[u]);
            s += acc[u]; q2 += acc[u] * acc[u];
        }
        *(uint4*)(y + ((long)b * HW2 + (long)(i0 + dr) * W2 + jbase + jj) * 128 + cg * 8) = outv;
    }
#pragma unroll
    for (int off = 32; off; off >>= 1) {
        s += __shfl_down(s, off);
        q2 += __shfl_down(q2, off);
    }
    __shared__ float r1[4], r2[4];
    if ((t & 63) == 0) { r1[t >> 6] = s; r2[t >> 6] = q2; }
    __syncthreads();
    if (t == 0) {
        int slot = (blockIdx.y * 8 + blockIdx.x) & 63;
        atomicAdd(lnS + ((long)b * 64 + slot) * 16, r1[0] + r1[1] + r1[2] + r1[3]);
        atomicAdd(lnQ + ((long)b * 64 + slot) * 16, r2[0] + r2[1] + r2[2] + r2[3]);
    }
}

// ---- fused MLP (512 thr): pw1 -> pw2, residual recomputed; W2 prefetch hoisted --
__global__ __launch_bounds__(512) void k_mlp(const u16* __restrict__ D,
                                             const u16* __restrict__ Wp1,
                                             const u16* __restrict__ Wp2,
                                             const float* __restrict__ b1p,
                                             const float* __restrict__ b2p,
                                             const u16* __restrict__ resA,
                                             u16* __restrict__ Yout,
                                             const float* __restrict__ lnS,
                                             const float* __restrict__ lnQ,
                                             const float* __restrict__ wbv,
                                             const float* __restrict__ wgs,
                                             const float* __restrict__ bnS,
                                             const float* __restrict__ bnQ,
                                             const float* __restrict__ g1,
                                             const float* __restrict__ b1v) {
    __shared__ __align__(16) u16 lA[16384];
    __shared__ __align__(16) u16 lB[16384];
    __shared__ float s1[128], s2[128], sA[128], sB[128], lnred[2];
    const int t = threadIdx.x;
    const int lane = t & 63, w = t >> 6, wr = w & 1, wc = w >> 1;
    const int r15 = lane & 15, kq = lane >> 4;
    const int b = blockIdx.z, m0 = blockIdx.y * 128;

    if (t < 64) {
        float s = lnS[((long)b * 64 + t) * 16];
        float q = lnQ[((long)b * 64 + t) * 16];
#pragma unroll
        for (int off = 32; off; off >>= 1) {
            s += __shfl_down(s, off);
            q += __shfl_down(q, off);
        }
        if (t == 0) { lnred[0] = s; lnred[1] = q; }
    }
    __syncthreads();
    const float invN = 1.0f / 2097152.0f;
    float mu = lnred[0] * invN;
    float var = lnred[1] * invN - mu * mu;
    const float rs = rsqrtf(var + 1e-5f);
    if (t < 128) {
        s1[t] = b1p[t] + wbv[t] - mu * rs * wgs[t];
        s2[t] = b2p[t];
        const float invN1 = 1.0f / 131072.0f;
        float mu1 = bnS[(long)t * 16] * invN1;
        float var1 = bnQ[(long)t * 16] * invN1 - mu1 * mu1;
        float rs1 = rsqrtf(var1 + 1e-5f);
        float sc1 = rs1 * g1[t];
        sA[t] = sc1;
        sB[t] = b1v[t] - mu1 * sc1;
    }

    const u16* Ab = D + ((long)b * HW2 + m0) * 128;
    uint4 ga[4], gb[4];
#pragma unroll
    for (int i = 0; i < 4; ++i) {
        int s = i * 512 + t, row = s >> 4, seg = s & 15;
        ga[i] = *(const uint4*)(Ab + (long)row * 128 + seg * 8);
        gb[i] = *(const uint4*)(Wp1 + (long)row * 128 + seg * 8);
    }
#pragma unroll
    for (int i = 0; i < 4; ++i) {
        int s = i * 512 + t, row = s >> 4, seg = s & 15;
        int off = (seg >> 3) * 16384 + row * 128 + 16 * ((seg & 7) ^ (row & 7));
        *(uint4*)((char*)lA + off) = ga[i];
        *(uint4*)((char*)lB + off) = gb[i];
    }
    __syncthreads();
    // prefetch pw2 weights EARLY (hides under GEMM1 MFMA)
#pragma unroll
    for (int i = 0; i < 4; ++i) {
        int s = i * 512 + t, row = s >> 4, seg = s & 15;
        gb[i] = *(const uint4*)(Wp2 + (long)row * 128 + seg * 8);
    }

    f32x4 acc[4][2];
#pragma unroll
    for (int i = 0; i < 4; ++i)
#pragma unroll
        for (int j = 0; j < 2; ++j) acc[i][j] = (f32x4){0.f, 0.f, 0.f, 0.f};
#pragma unroll
    for (int chunk = 0; chunk < 2; ++chunk)
#pragma unroll
        for (int ks = 0; ks < 2; ++ks) {
            const int ch = ks * 4 + kq;
            short8 af[4], bfv[2];
#pragma unroll
            for (int mi = 0; mi < 4; ++mi) {
                int row = wr * 64 + mi * 16 + r15;
                af[mi] = *(const short8*)((const char*)lA + chunk * 16384 +
                                          row * 128 + 16 * (ch ^ (row & 7)));
            }
#pragma unroll
            for (int ni = 0; ni < 2; ++ni) {
                int row = wc * 32 + ni * 16 + r15;
                bfv[ni] = *(const short8*)((const char*)lB + chunk * 16384 +
                                           row * 128 + 16 * (ch ^ (row & 7)));
            }
#pragma unroll
            for (int mi = 0; mi < 4; ++mi)
#pragma unroll
                for (int ni = 0; ni < 2; ++ni)
                    acc[mi][ni] = __builtin_amdgcn_mfma_f32_16x16x32_bf16(
                        af[mi], bfv[ni], acc[mi][ni], 0, 0, 0);
        }
    __syncthreads();   // all lA/lB reads complete

    // bounce1: gelu(rs*acc + s1[ch]) -> lA in GEMM-A k-major layout (k = ch)
#pragma unroll
    for (int mi = 0; mi < 4; ++mi)
#pragma unroll
        for (int ni = 0; ni < 2; ++ni)
#pragma unroll
            for (int r = 0; r < 4; ++r) {
                int row = wr * 64 + mi * 16 + kq * 4 + r;
                int col = wc * 32 + ni * 16 + r15;
                float v = gelu_f(rs * acc[mi][ni][r] + s1[col]);
                lA[(col >> 6) * 8192 + row * 64 +
                   8 * (((col >> 3) & 7) ^ (row & 7)) + (col & 7)] = f2bf(v);
            }
#pragma unroll
    for (int i = 0; i < 4; ++i) {
        int s = i * 512 + t, row = s >> 4, seg = s & 15;
        int off = (seg >> 3) * 16384 + row * 128 + 16 * ((seg & 7) ^ (row & 7));
        *(uint4*)((char*)lB + off) = gb[i];
    }
    __syncthreads();

    // GEMM2
#pragma unroll
    for (int i = 0; i < 4; ++i)
#pragma unroll
        for (int j = 0; j < 2; ++j) acc[i][j] = (f32x4){0.f, 0.f, 0.f, 0.f};
#pragma unroll
    for (int chunk = 0; chunk < 2; ++chunk)
#pragma unroll
        for (int ks = 0; ks < 2; ++ks) {
            const int ch = ks * 4 + kq;
            short8 af[4], bfv[2];
#pragma unroll
            for (int mi = 0; mi < 4; ++mi) {
                int row = wr * 64 + mi * 16 + r15;
                af[mi] = *(const short8*)((const char*)lA + chunk * 16384 +
                                          row * 128 + 16 * (ch ^ (row & 7)));
            }
#pragma unroll
            for (int ni = 0; ni < 2; ++ni) {
                int row = wc * 32 + ni * 16 + r15;
                bfv[ni] = *(const short8*)((const char*)lB + chunk * 16384 +
                                           row * 128 + 16 * (ch ^ (row & 7)));
            }
#pragma unroll
            for (int mi = 0; mi < 4; ++mi)
#pragma unroll
                for (int ni = 0; ni < 2; ++ni)
                    acc[mi][ni] = __builtin_amdgcn_mfma_f32_16x16x32_bf16(
                        af[mi], bfv[ni], acc[mi][ni], 0, 0, 0);
        }
    __syncthreads();

#pragma unroll
    for (int mi = 0; mi < 4; ++mi)
#pragma unroll
        for (int ni = 0; ni < 2; ++ni)
#pragma unroll
            for (int r = 0; r < 4; ++r) {
                int row = wr * 64 + mi * 16 + kq * 4 + r;
                int col = wc * 32 + ni * 16 + r15;
                lA[row * 128 + (col ^ ((row & 7) << 3))] = f2bf(acc[mi][ni][r]);
            }
    __syncthreads();

    const u16* Ra = resA + ((long)b * HW2 + m0) * 128;
    u16* Cb = Yout + ((long)b * HW2 + m0) * 128;
    {
        int row = t >> 2, quarter = (t & 3) * 32;
        int sx = (row & 7) << 3;
#pragma unroll
        for (int q = 0; q < 4; ++q) {
            int c = quarter + q * 8;
            uint4 raw = *(const uint4*)(lA + row * 128 + (c ^ sx));
            uint4 rr = *(const uint4*)(Ra + (long)row * 128 + c);
            u16* pv = (u16*)&raw;
            const u16* rv = (const u16*)&rr;
#pragma unroll
            for (int u = 0; u < 8; ++u) {
                float hres = gelu_f(bf2f(rv[u]) * sA[c + u] + sB[c + u]);
                pv[u] = f2bf(bf2f(pv[u]) + s2[c + u] + hres);
            }
            *(uint4*)(Cb + (long)row * 128 + c) = raw;
        }
    }
}

// ---- second moment partials: 256 blocks x 512 px (full-GPU utilization) ----
__global__ __launch_bounds__(256) void k_moment(const u16* __restrict__ Y,
                                                float* __restrict__ M2p,
                                                float* __restrict__ csum) {
    __shared__ __align__(16) u16 T[8192];
    __shared__ float cred[16][16][8];
    const int t = threadIdx.x;
    const int lane = t & 63, w = t >> 6, wr = w >> 1, wc = w & 1;
    const int r15 = lane & 15, kq = lane >> 4;
    const long px0 = (long)blockIdx.x * 512;
    float cs[8] = {};

    f32x4 acc[4][4];
#pragma unroll
    for (int i = 0; i < 4; ++i)
#pragma unroll
        for (int j = 0; j < 4; ++j) acc[i][j] = (f32x4){0.f, 0.f, 0.f, 0.f};

    for (int it = 0; it < 8; ++it) {
        uint4 rv[4];
#pragma unroll
        for (int i = 0; i < 4; ++i) {
            int s = i * 256 + t;
            int px = s >> 4, ch8 = (s & 15) * 8;
            rv[i] = *(const uint4*)(Y + (px0 + it * 64 + px) * 128 + ch8);
        }
#pragma unroll
        for (int i = 0; i < 4; ++i) {
            const u16* pv = (const u16*)&rv[i];
#pragma unroll
            for (int u = 0; u < 8; ++u) cs[u] += bf2f(pv[u]);
        }
        __syncthreads();
#pragma unroll
        for (int i = 0; i < 4; ++i) {
            int s = i * 256 + t;
            int px = s >> 4, ch8 = (s & 15) * 8;
            const u16* pv = (const u16*)&rv[i];
#pragma unroll
            for (int u = 0; u < 8; ++u) {
                int row = ch8 + u;
                T[row * 64 + 8 * ((px >> 3) ^ (row & 7)) + (px & 7)] = pv[u];
            }
        }
        __syncthreads();
#pragma unroll
        for (int ks = 0; ks < 2; ++ks) {
            const int ch = ks * 4 + kq;
            short8 af[4], bfv[4];
#pragma unroll
            for (int mi = 0; mi < 4; ++mi) {
                int row = wr * 64 + mi * 16 + r15;
                af[mi] = *(const short8*)(T + row * 64 + 8 * (ch ^ (row & 7)));
            }
#pragma unroll
            for (int ni = 0; ni < 4; ++ni) {
                int row = wc * 64 + ni * 16 + r15;
                bfv[ni] = *(const short8*)(T + row * 64 + 8 * (ch ^ (row & 7)));
            }
#pragma unroll
            for (int mi = 0; mi < 4; ++mi)
#pragma unroll
                for (int ni = 0; ni < 4; ++ni)
                    acc[mi][ni] = __builtin_amdgcn_mfma_f32_16x16x32_bf16(
                        af[mi], bfv[ni], acc[mi][ni], 0, 0, 0);
        }
    }
    {
        int g = t & 15, m = t >> 4;
#pragma unroll
        for (int u = 0; u < 8; ++u) cred[m][g][u] = cs[u];
    }
    __syncthreads();
    if (t < 128) {
        float s = 0.f;
#pragma unroll
        for (int m = 0; m < 16; ++m) s += cred[m][t >> 3][t & 7];
        atomicAdd(csum + (long)t * 16, s);
    }
    float* Mb = M2p + (long)blockIdx.x * 16384;
#pragma unroll
    for (int mi = 0; mi < 4; ++mi)
#pragma unroll
        for (int ni = 0; ni < 4; ++ni)
#pragma unroll
            for (int r = 0; r < 4; ++r) {
                int row = wr * 64 + mi * 16 + kq * 4 + r;
                int col = wc * 64 + ni * 16 + r15;
                Mb[row * 128 + col] = acc[mi][ni][r];
            }
}

// ---- reduce 256 M2 partials -> M2 dense ----
__global__ __launch_bounds__(256) void k_m2red(const float* __restrict__ M2p,
                                               float* __restrict__ M2) {
    int e = blockIdx.x * 256 + threadIdx.x;
    float s = 0.f;
    for (int p = 0; p < 256; ++p) s += M2p[(long)p * 16384 + e];
    M2[e] = s;
}

// ---- combine: per-out-channel BN2 scale/shift ----
__global__ __launch_bounds__(128) void k_statcomb(const float* __restrict__ w_c2,
                                                  const float* __restrict__ M2,
                                                  const float* __restrict__ csum,
                                                  const float* __restrict__ g,
                                                  const float* __restrict__ bb,
                                                  float* __restrict__ scsh) {
    __shared__ float wl[128];
    __shared__ float red[2][2];
    const int o = blockIdx.x, c = threadIdx.x;
    wl[c] = w_c2[o * 128 + c];
    __syncthreads();
    const float* m2r = M2 + c * 128;
    float tmp = 0.f;
#pragma unroll
    for (int c2 = 0; c2 < 128; c2 += 4) {
        float4 m = *(const float4*)(m2r + c2);
        tmp += m.x * wl[c2] + m.y * wl[c2 + 1] + m.z * wl[c2 + 2] + m.w * wl[c2 + 3];
    }
    float s2p = wl[c] * tmp;
    float mup = wl[c] * csum[(long)c * 16];
#pragma unroll
    for (int off = 32; off; off >>= 1) {
        s2p += __shfl_down(s2p, off);
        mup += __shfl_down(mup, off);
    }
    if ((c & 63) == 0) { red[0][c >> 6] = s2p; red[1][c >> 6] = mup; }
    __syncthreads();
    if (c == 0) {
        float s2 = (red[0][0] + red[0][1]) / NPIX;
        float mu = (red[1][0] + red[1][1]) / NPIX;
        float var = s2 - mu * mu;
        float rs = rsqrtf(var + 1e-5f);
        float sc = g[o] * rs;
        scsh[o] = sc;
        scsh[512 + o] = bb[o] - mu * sc;
    }
}

// ---- conv2 + BN2 + GELU + IDWT; weight prefetch hoisted before MFMA ----
__global__ __launch_bounds__(512) void k_conv2_idwt(const u16* __restrict__ Y,
                                                    const u16* __restrict__ Wc,
                                                    const float* __restrict__ scsh,
                                                    float* __restrict__ out) {
    __shared__ __align__(16) u16 lA[16384];
    __shared__ __align__(16) u16 lB[8192];
    __shared__ float sparam[1024];
    const int t = threadIdx.x;
    const int lane = t & 63, w = t >> 6, wr = w & 1, wc = w >> 1;
    const int r15 = lane & 15, kq = lane >> 4;
    const int b = blockIdx.y, n0 = blockIdx.x;
#pragma unroll
    for (int u = 0; u < 2; ++u) sparam[t + u * 512] = scsh[t + u * 512];

    const u16* Yb = Y + ((long)b * HW2 + (long)n0 * 64) * 128;
    uint4 rb2[2], ra4[4];
#pragma unroll
    for (int i = 0; i < 2; ++i) {
        int s = i * 512 + t, row = s >> 4, seg = s & 15;
        rb2[i] = *(const uint4*)(Yb + (long)row * 128 + seg * 8);
    }
#define GLOADA(q)                                                                \
    {                                                                            \
        _Pragma("unroll")                                                        \
        for (int i = 0; i < 4; ++i) {                                            \
            int s = i * 512 + t, row = s >> 4, seg = s & 15;                     \
            ra4[i] = *(const uint4*)(Wc + (long)((q) * 128 + row) * 128 + seg * 8); \
        }                                                                        \
    }
#define LWRITEA()                                                                \
    {                                                                            \
        _Pragma("unroll")                                                        \
        for (int i = 0; i < 4; ++i) {                                            \
            int s = i * 512 + t, row = s >> 4, seg = s & 15;                     \
            *(uint4*)((char*)lA + (seg >> 3) * 16384 + row * 128 +               \
                      16 * ((seg & 7) ^ (row & 7))) = ra4[i];                    \
        }                                                                        \
    }
    GLOADA(0)
#pragma unroll
    for (int i = 0; i < 2; ++i) {
        int s = i * 512 + t, row = s >> 4, seg = s & 15;
        *(uint4*)((char*)lB + (seg >> 3) * 8192 + row * 128 +
                  16 * ((seg & 7) ^ (row & 7))) = rb2[i];
    }
    LWRITEA()
    __syncthreads();

    u32 sbp[4][4][2];
#pragma unroll
    for (int q = 0; q < 4; ++q) {
        if (q < 3) GLOADA(q + 1)   // issue next-phase weight loads before MFMA
        f32x4 acc[4];
#pragma unroll
        for (int mi = 0; mi < 4; ++mi) acc[mi] = (f32x4){0.f, 0.f, 0.f, 0.f};
#pragma unroll
        for (int chunk = 0; chunk < 2; ++chunk)
#pragma unroll
            for (int ks = 0; ks < 2; ++ks) {
                const int ch = ks * 4 + kq;
                short8 af[4], bfv;
#pragma unroll
                for (int mi = 0; mi < 4; ++mi) {
                    int row = wr * 64 + mi * 16 + r15;
                    af[mi] = *(const short8*)((const char*)lA + chunk * 16384 +
                                              row * 128 + 16 * (ch ^ (row & 7)));
                }
                {
                    int row = wc * 16 + r15;
                    bfv = *(const short8*)((const char*)lB + chunk * 8192 +
                                           row * 128 + 16 * (ch ^ (row & 7)));
                }
#pragma unroll
                for (int mi = 0; mi < 4; ++mi)
                    acc[mi] = __builtin_amdgcn_mfma_f32_16x16x32_bf16(
                        af[mi], bfv, acc[mi], 0, 0, 0);
            }
#pragma unroll
        for (int mi = 0; mi < 4; ++mi)
#pragma unroll
            for (int rp = 0; rp < 2; ++rp) {
                int c0 = q * 128 + wr * 64 + mi * 16 + kq * 4 + rp * 2;
                float v0 = gelu_f(acc[mi][rp * 2] * sparam[c0] + sparam[512 + c0]);
                float v1 = gelu_f(acc[mi][rp * 2 + 1] * sparam[c0 + 1] + sparam[512 + c0 + 1]);
                sbp[q][mi][rp] = (u32)f2bf(v0) | ((u32)f2bf(v1) << 16);
            }
        if (q < 3) {
            __syncthreads();
            LWRITEA()
            __syncthreads();
        }
    }
    const int i = n0 >> 1;
    const int j = (n0 & 1) * 64 + wc * 16 + r15;
#pragma unroll
    for (int mi = 0; mi < 4; ++mi)
#pragma unroll
        for (int rp = 0; rp < 2; ++rp) {
            u32 p0 = sbp[0][mi][rp], p1 = sbp[1][mi][rp];
            u32 p2 = sbp[2][mi][rp], p3 = sbp[3][mi][rp];
#pragma unroll
            for (int e = 0; e < 2; ++e) {
                int c = wr * 64 + mi * 16 + kq * 4 + rp * 2 + e;
                float ll = bf2f(e ? (u16)(p0 >> 16) : (u16)(p0 & 0xFFFF));
                float lh = bf2f(e ? (u16)(p1 >> 16) : (u16)(p1 & 0xFFFF));
                float hl = bf2f(e ? (u16)(p2 >> 16) : (u16)(p2 & 0xFFFF));
                float hh = bf2f(e ? (u16)(p3 >> 16) : (u16)(p3 & 0xFFFF));
                long ob = (((long)(b * Cc + c) * Hh + 2 * i) * Wf + 2 * j);
                union { float2 v; u64 u; } w0, w1;
                w0.v = make_float2((ll + lh + hl + hh) * 0.5f, (ll + lh - hl - hh) * 0.5f);
                w1.v = make_float2((ll - lh + hl - hh) * 0.5f, (ll - lh - hl + hh) * 0.5f);
                __builtin_nontemporal_store(w0.u, (u64*)(out + ob));
                __builtin_nontemporal_store(w1.u, (u64*)(out + ob + Wf));
            }
        }
#undef GLOADA
#undef LWRITEA
}

extern "C" void kernel_launch(void* const* d_in, const int* in_sizes, int n_in,
                              void* d_out, int out_size, void* d_ws, size_t ws_size,
                              hipStream_t stream) {
    const float* x     = (const float*)d_in[0];
    const float* w_c1  = (const float*)d_in[1];
    const float* bn1_g = (const float*)d_in[3];
    const float* bn1_b = (const float*)d_in[4];
    const float* dw_w  = (const float*)d_in[5];
    const float* dw_b  = (const float*)d_in[6];
    const float* gn_g  = (const float*)d_in[7];
    const float* gn_b  = (const float*)d_in[8];
    const float* pw1_w = (const float*)d_in[9];
    const float* pw1_b = (const float*)d_in[10];
    const float* pw2_w = (const float*)d_in[11];
    const float* pw2_b = (const float*)d_in[12];
    const float* w_c2  = (const float*)d_in[13];
    const float* bn2_g = (const float*)d_in[15];
    const float* bn2_b = (const float*)d_in[16];
    float* out = (float*)d_out;

    const size_t n128 = (size_t)Bq * Cc * HW2;
    u16* bufA = (u16*)d_ws;
    u16* bufD = bufA + n128;
    u16* bufY = bufD + n128;
    u16* wb   = bufY + n128;
    float* stats = (float*)(wb + 163840);
    float* M2p = stats + 49152;    // 256 x 16384 f32 partials (16 MB)
    size_t need = (3 * n128 + 163840) * 2 + (49152 + 256 * 16384) * 4;
    if (ws_size < need) return;

    float* bn1_sum = stats;
    float* bn1_sq  = stats + 2048;
    float* ln_sum  = stats + 4096;
    float* ln_sq   = stats + 12288;
    float* csum    = stats + 20480;
    float* M2      = stats + 22528;
    float* scsh    = stats + 38912;
    float* wbv     = stats + 39936;
    float* wgs     = stats + 40064;

    // 0. weights -> bf16 + stats zeroing + LN-fold vectors (block 640)
    k_wconv<<<641, 256, 0, stream>>>(w_c1, pw1_w, pw2_w, w_c2, gn_g, gn_b,
                                     wb, wbv, wgs, stats);

    // 1. fused DWT + conv1 + BN1 stats
    k_conv1<<<dim3(1, 128, 8), 512, 0, stream>>>(x, wb, bufA, bn1_sum, bn1_sq);

    // 2. depthwise 3x3, 4-row tiles, fused BN1+gelu on load + LN stats
    k_dwconv<<<dim3(8, 32, 8), 256, 0, stream>>>(bufA, bufD, dw_w, dw_b,
                                                 bn1_sum, bn1_sq, bn1_g, bn1_b,
                                                 ln_sum, ln_sq);

    // 3. fused MLP (512 thr): pw1 (LN-folded + gelu) -> pw2 (+bias + residual)
    k_mlp<<<dim3(1, 128, 8), 512, 0, stream>>>(
        bufD, wb + 65536, wb + 81920, pw1_b, pw2_b, bufA, bufY,
        ln_sum, ln_sq, wbv, wgs, bn1_sum, bn1_sq, bn1_g, bn1_b);

    // 4. BN2 stats: per-block M2 partials (256 blocks) + reduce + combine
    k_moment<<<256, 256, 0, stream>>>(bufY, M2p, csum);
    k_m2red<<<64, 256, 0, stream>>>(M2p, M2);
    k_statcomb<<<512, 128, 0, stream>>>(w_c2, M2, csum, bn2_g, bn2_b, scsh);

    // 5. conv2 + BN2 + gelu + IDWT -> out (NT stores, hoisted prefetch)
    k_conv2_idwt<<<dim3(256, 8), 512, 0, stream>>>(bufY, wb + 98304, scsh, out);
}